// Round 2
// baseline (278.179 us; speedup 1.0000x reference)
//
#include <hip/hip_runtime.h>
#include <hip/hip_bf16.h>

typedef __bf16 b16;
typedef __bf16 b16x8 __attribute__((ext_vector_type(8)));
typedef float  f32x4 __attribute__((ext_vector_type(4)));

#define B_   64
#define N_   196
#define C_   768
#define H_   12
#define HD_  64
#define TOK  (B_*N_)      // 12544
#define SCALE 0.125f

// ---------------------------------------------------------------- transpose+cvt
// out[c][r] = (bf16) in[r][c];  R,C multiples of 32
__global__ __launch_bounds__(256) void k_transpose_cvt(const float* __restrict__ in,
                                                       b16* __restrict__ out, int R, int C){
  __shared__ b16 tile[32][33];
  int tx = threadIdx.x, ty = threadIdx.y;
  int bx = blockIdx.x, by = blockIdx.y;
  int c = bx*32 + tx;
  #pragma unroll
  for (int i = 0; i < 32; i += 8){
    int r = by*32 + ty + i;
    tile[ty+i][tx] = (b16)in[(long)r*C + c];
  }
  __syncthreads();
  int rr = by*32 + tx;
  #pragma unroll
  for (int i = 0; i < 32; i += 8){
    int cc = bx*32 + ty + i;
    out[(long)cc*R + rr] = tile[tx][ty+i];
  }
}

// ---------------------------------------------------------------- K = k^T k, ksum
__global__ __launch_bounds__(256) void k_kprep(const float* __restrict__ k_ext,
                                               float* __restrict__ Kmat, float* __restrict__ ksum){
  __shared__ float ks[N_][HD_];   // 50176 B
  int tid = threadIdx.x;
  for (int i = tid; i < N_*HD_; i += 256) ks[i/HD_][i%HD_] = k_ext[i];
  __syncthreads();
  int i = tid >> 2;          // 0..63
  int j0 = (tid & 3) * 16;   // 16 columns
  float acc[16];
  #pragma unroll
  for (int t = 0; t < 16; ++t) acc[t] = 0.f;
  for (int p = 0; p < N_; ++p){
    float ki = ks[p][i];
    const float4* kp = (const float4*)&ks[p][j0];
    #pragma unroll
    for (int t = 0; t < 4; ++t){
      float4 kv = kp[t];
      acc[t*4+0] += ki*kv.x; acc[t*4+1] += ki*kv.y;
      acc[t*4+2] += ki*kv.z; acc[t*4+3] += ki*kv.w;
    }
  }
  #pragma unroll
  for (int t = 0; t < 16; ++t) Kmat[i*64 + j0 + t] = acc[t];
  if (tid < 64){
    float s = 0.f;
    for (int p = 0; p < N_; ++p) s += ks[p][tid];
    ksum[tid] = s;
  }
}

// ---------------------------------------------------------------- tiled bf16 MFMA GEMM
// A [12544 x 768] (MODE0: f32 x, cvt in staging; MODE1: bf16 O_buf)
// BT [Ncols x 768] bf16 row-major (pre-transposed weights)
// MODE0: scatter to q_buf/v_buf bf16 [b,h,n,d];  MODE1: f32 out + bias
template<int MODE>
__global__ __launch_bounds__(256, 2) void k_gemm(const void* __restrict__ Ap,
                                                 const b16* __restrict__ BT,
                                                 b16* __restrict__ qout, b16* __restrict__ vout,
                                                 float* __restrict__ fout, const float* __restrict__ bias){
  const int NT = (MODE == 0) ? 12 : 6;
  int bid = blockIdx.x;
  int rt = bid / NT, ct = bid % NT;
  int brow = rt*128, bcol = ct*128;
  __shared__ b16 As[128*32];
  __shared__ b16 Bs[128*32];
  int tid = threadIdx.x, lane = tid & 63, wid = tid >> 6;
  int wr = wid >> 1, wc = wid & 1;
  f32x4 acc[4][4];
  #pragma unroll
  for (int m = 0; m < 4; ++m)
    #pragma unroll
    for (int n = 0; n < 4; ++n) acc[m][n] = (f32x4){0.f,0.f,0.f,0.f};

  for (int kt = 0; kt < 768/32; ++kt){
    #pragma unroll
    for (int hh = 0; hh < 2; ++hh){
      int c = tid + hh*256;           // 0..511
      int r = c >> 2, g = c & 3;
      // swizzle: 4 groups per 64B row -> XOR with (r&3)  (bijective, in-bounds)
      if constexpr (MODE == 0){
        const float* A = (const float*)Ap;
        const float4* src = (const float4*)(A + (long)(brow + r)*768 + kt*32 + g*8);
        float4 f0 = src[0], f1 = src[1];
        b16x8 v; v[0]=(b16)f0.x; v[1]=(b16)f0.y; v[2]=(b16)f0.z; v[3]=(b16)f0.w;
                 v[4]=(b16)f1.x; v[5]=(b16)f1.y; v[6]=(b16)f1.z; v[7]=(b16)f1.w;
        *(b16x8*)((char*)As + r*64 + ((g ^ (r&3))<<4)) = v;
      } else {
        const b16* A = (const b16*)Ap;
        *(b16x8*)((char*)As + r*64 + ((g ^ (r&3))<<4)) =
            *(const b16x8*)(A + (long)(brow + r)*768 + kt*32 + g*8);
      }
      *(b16x8*)((char*)Bs + r*64 + ((g ^ (r&3))<<4)) =
          *(const b16x8*)(BT + (long)(bcol + r)*768 + kt*32 + g*8);
    }
    __syncthreads();
    b16x8 af[4], bf[4];
    #pragma unroll
    for (int m = 0; m < 4; ++m){
      int row = wr*64 + m*16 + (lane & 15);
      af[m] = *(const b16x8*)((const char*)As + row*64 + (((lane>>4) ^ (row&3))<<4));
    }
    #pragma unroll
    for (int n = 0; n < 4; ++n){
      int row = wc*64 + n*16 + (lane & 15);
      bf[n] = *(const b16x8*)((const char*)Bs + row*64 + (((lane>>4) ^ (row&3))<<4));
    }
    #pragma unroll
    for (int m = 0; m < 4; ++m)
      #pragma unroll
      for (int n = 0; n < 4; ++n)
        acc[m][n] = __builtin_amdgcn_mfma_f32_16x16x32_bf16(af[m], bf[n], acc[m][n], 0, 0, 0);
    __syncthreads();
  }

  if constexpr (MODE == 0){
    #pragma unroll
    for (int m = 0; m < 4; ++m){
      #pragma unroll
      for (int n = 0; n < 4; ++n){
        int col = bcol + wc*64 + n*16 + (lane & 15);
        int two = (col >= 768) ? 1 : 0;
        int hc = col - two*768;
        int hh = hc >> 6, d = hc & 63;
        b16* dst = two ? vout : qout;
        #pragma unroll
        for (int j = 0; j < 4; ++j){
          int r2 = brow + wr*64 + m*16 + ((lane>>4)<<2) + j;
          int bq = r2 / 196;
          int nn = r2 - bq*196;
          dst[((bq*12 + hh)*196 + nn)*64 + d] = (b16)acc[m][n][j];
        }
      }
    }
  } else {
    #pragma unroll
    for (int m = 0; m < 4; ++m){
      #pragma unroll
      for (int n = 0; n < 4; ++n){
        int col = bcol + wc*64 + n*16 + (lane & 15);
        float bv = bias[col];
        #pragma unroll
        for (int j = 0; j < 4; ++j){
          int r2 = brow + wr*64 + m*16 + ((lane>>4)<<2) + j;
          fout[(long)r2*768 + col] = acc[m][n][j] + bv;
        }
      }
    }
  }
}

// ---------------------------------------------------------------- fused q*ksum + v stats
// stats layout: [0..11] S1(q.ksum), [12..23] S2(qKq), [24..35] Vsum, [36..47] Vsum2
__global__ __launch_bounds__(256) void k_stats(const b16* __restrict__ q, const b16* __restrict__ v,
                                               const float* __restrict__ ksum, float* __restrict__ stats){
  __shared__ float ksh[64];
  __shared__ float bins[12][3];
  int tid = threadIdx.x;
  if (tid < 64) ksh[tid] = ksum[tid];
  if (tid < 36) ((float*)bins)[tid] = 0.f;
  __syncthreads();
  const long NCH = (long)9633792/8; // 1204224
  for (long i = (long)blockIdx.x*256 + tid; i < NCH; i += (long)gridDim.x*256){
    long e0 = i*8;
    int head = (int)(e0 / (196*64)) % 12;
    b16x8 q8 = *(const b16x8*)(q + e0);
    b16x8 v8 = *(const b16x8*)(v + e0);
    int d0 = (int)(e0 & 63);
    float s1 = 0.f, vs = 0.f, vs2 = 0.f;
    #pragma unroll
    for (int j = 0; j < 8; ++j){
      float qf = (float)q8[j], vf = (float)v8[j];
      s1 += qf*ksh[d0+j]; vs += vf; vs2 += vf*vf;
    }
    atomicAdd(&bins[head][0], s1);
    atomicAdd(&bins[head][1], vs);
    atomicAdd(&bins[head][2], vs2);
  }
  __syncthreads();
  if (tid < 12){
    atomicAdd(&stats[tid],      bins[tid][0]);
    atomicAdd(&stats[24+tid],   bins[tid][1]);
    atomicAdd(&stats[36+tid],   bins[tid][2]);
  }
}

// ---------------------------------------------------------------- S2 = sum q^T K q per head
__global__ __launch_bounds__(256) void k_qform(const b16* __restrict__ q,
                                               const float* __restrict__ Kmat,
                                               float* __restrict__ stats){
  __shared__ float bins[12];
  int tid = threadIdx.x;
  if (tid < 12) bins[tid] = 0.f;
  __syncthreads();
  long token = (long)blockIdx.x*256 + tid;   // < 150528 exactly
  float qr[64];
  const b16x8* qp = (const b16x8*)(q + token*64);
  #pragma unroll
  for (int j = 0; j < 8; ++j){
    b16x8 t = qp[j];
    #pragma unroll
    for (int e = 0; e < 8; ++e) qr[j*8+e] = (float)t[e];
  }
  float s2 = 0.f;
  #pragma unroll
  for (int i2 = 0; i2 < 64; ++i2){
    const float4* kr = (const float4*)(Kmat + i2*64);
    float a = 0.f;
    #pragma unroll
    for (int j4 = 0; j4 < 16; ++j4){
      float4 kv = kr[j4];
      a += kv.x*qr[j4*4] + kv.y*qr[j4*4+1] + kv.z*qr[j4*4+2] + kv.w*qr[j4*4+3];
    }
    s2 += a * qr[i2];
  }
  int head = (int)(token / 196) % 12;
  atomicAdd(&bins[head], s2);
  __syncthreads();
  if (tid < 12) atomicAdd(&stats[12+tid], bins[tid]);
}

// ---------------------------------------------------------------- finalize per-head coefs
__global__ void k_final(const float* __restrict__ stats, const float* __restrict__ gamma,
                        const float* __restrict__ beta, float* __restrict__ coef){
  int h = threadIdx.x;
  if (h < 12){
    const float cntS = 2458624.f, cntV = 802816.f;
    float S1 = stats[h], S2 = stats[12+h], VS = stats[24+h], VS2 = stats[36+h];
    float ms = S1/cntS;
    float vars = S2/cntS - ms*ms;
    float alpha = gamma[h]*SCALE*rsqrtf(vars + 1e-5f);
    float mv = VS/cntV;
    float varv = VS2/cntV - mv*mv;
    float a = gamma[h]*rsqrtf(varv + 1e-5f);
    coef[h*4+0] = alpha;
    coef[h*4+1] = a;
    coef[h*4+2] = beta[h] - a*mv;
  }
}

// ---------------------------------------------------------------- fused attention per (b,h)
__global__ __launch_bounds__(256, 2) void k_attn(const b16* __restrict__ qb, const b16* __restrict__ vb,
                                                 const float* __restrict__ k_ext,
                                                 const float* __restrict__ attn_bias,
                                                 const float* __restrict__ coef,
                                                 b16* __restrict__ Ob){
  __shared__ b16 ksh[196*64];        // swizzled [p][d], 25088 B
  __shared__ b16 vsh[64*216];        // [d][p] stride 216, 27648 B
  __shared__ b16 psh[4][16*200];     // per-wave P rows, stride 200, 25600 B
  __shared__ float bsh[196];

  int tid = threadIdx.x, lane = tid & 63, wid = tid >> 6;
  int bh = blockIdx.x;
  int h = bh % 12, b = bh / 12;
  const b16* qt = qb + (long)bh*N_*64;
  const b16* vt = vb + (long)bh*N_*64;
  float alpha = coef[h*4+0], av = coef[h*4+1], cv = coef[h*4+2];

  // stage K (f32 -> bf16, XOR-swizzled rows of 128B: 8 groups, XOR (p&7) bijective)
  for (int c = tid; c < 196*8; c += 256){
    int p = c >> 3, g = c & 7;
    const float4* src = (const float4*)(k_ext + p*64 + g*8);
    float4 f0 = src[0], f1 = src[1];
    b16x8 v; v[0]=(b16)f0.x; v[1]=(b16)f0.y; v[2]=(b16)f0.z; v[3]=(b16)f0.w;
             v[4]=(b16)f1.x; v[5]=(b16)f1.y; v[6]=(b16)f1.z; v[7]=(b16)f1.w;
    *(b16x8*)((char*)ksh + p*128 + ((g ^ (p&7))<<4)) = v;
  }
  for (int p = tid; p < 196; p += 256) bsh[p] = attn_bias[p]*SCALE;
  // stage V transposed: coalesced global reads, b128 LDS writes
  {
    int d = tid & 63;
    for (int p0 = (tid>>6)*8; p0 < 196; p0 += 32){
      b16x8 w;
      #pragma unroll
      for (int j = 0; j < 8; ++j){
        int p = p0 + j;
        w[j] = (p < 196) ? vt[p*64 + d] : (b16)0.f;
      }
      *(b16x8*)((char*)vsh + d*432 + p0*2) = w;
    }
  }
  __syncthreads();

  for (int rt = wid; rt < 13; rt += 4){
    int n0 = rt*16;
    int qrow = n0 + (lane & 15); if (qrow > 195) qrow = 195;
    b16x8 a0 = *(const b16x8*)((const char*)qt + qrow*128 +      ((lane>>4)<<4));
    b16x8 a1 = *(const b16x8*)((const char*)qt + qrow*128 + 64 + ((lane>>4)<<4));

    f32x4 sc[13];
    #pragma unroll
    for (int ct = 0; ct < 13; ++ct){
      int p = ct*16 + (lane & 15); int pc = p > 195 ? 195 : p;
      b16x8 b0 = *(const b16x8*)((const char*)ksh + pc*128 + ((( (lane>>4))   ^ (pc&7))<<4));
      b16x8 b1 = *(const b16x8*)((const char*)ksh + pc*128 + (((4+(lane>>4))  ^ (pc&7))<<4));
      f32x4 z = {0.f,0.f,0.f,0.f};
      z = __builtin_amdgcn_mfma_f32_16x16x32_bf16(a0, b0, z, 0, 0, 0);
      z = __builtin_amdgcn_mfma_f32_16x16x32_bf16(a1, b1, z, 0, 0, 0);
      sc[ct] = z;
    }
    // logits + masked row-max
    int pcol = lane & 15;
    float mx[4] = {-1e30f,-1e30f,-1e30f,-1e30f};
    #pragma unroll
    for (int ct = 0; ct < 13; ++ct){
      int p = ct*16 + pcol;
      bool valid = (p < 196);
      float badd = valid ? bsh[p < 196 ? p : 0] : 0.f;
      #pragma unroll
      for (int j = 0; j < 4; ++j){
        float lv = valid ? (sc[ct][j]*alpha + badd) : -1e30f;
        sc[ct][j] = lv;
        mx[j] = fmaxf(mx[j], lv);
      }
    }
    #pragma unroll
    for (int off = 1; off < 16; off <<= 1)
      #pragma unroll
      for (int j = 0; j < 4; ++j) mx[j] = fmaxf(mx[j], __shfl_xor(mx[j], off, 64));
    float sm[4] = {0.f,0.f,0.f,0.f};
    #pragma unroll
    for (int ct = 0; ct < 13; ++ct)
      #pragma unroll
      for (int j = 0; j < 4; ++j){
        float e = __expf(sc[ct][j] - mx[j]);
        sc[ct][j] = e; sm[j] += e;
      }
    #pragma unroll
    for (int off = 1; off < 16; off <<= 1)
      #pragma unroll
      for (int j = 0; j < 4; ++j) sm[j] += __shfl_xor(sm[j], off, 64);
    float rs[4];
    #pragma unroll
    for (int j = 0; j < 4; ++j) rs[j] = 1.f/sm[j];

    // write P rows (p < 192) to per-wave LDS; keep ct=12 in regs
    b16* pw = psh[wid];
    #pragma unroll
    for (int ct = 0; ct < 12; ++ct){
      int p = ct*16 + pcol;
      #pragma unroll
      for (int j = 0; j < 4; ++j){
        int r = ((lane>>4)<<2) + j;
        pw[r*200 + p] = (b16)(sc[ct][j]*rs[j]);
      }
    }
    float pt12[4];
    #pragma unroll
    for (int j = 0; j < 4; ++j) pt12[j] = sc[12][j]*rs[j];

    // ensure all per-wave P LDS writes are visible before fragment reads
    __asm__ volatile("s_waitcnt lgkmcnt(0)" ::: "memory");
    __builtin_amdgcn_sched_barrier(0);

    // PV: 6 MFMA K-steps over p<192
    f32x4 o[4];
    #pragma unroll
    for (int dt = 0; dt < 4; ++dt) o[dt] = (f32x4){0.f,0.f,0.f,0.f};
    #pragma unroll
    for (int pt = 0; pt < 6; ++pt){
      b16x8 pa = *(const b16x8*)((const char*)pw + (lane&15)*400 + pt*64 + ((lane>>4)<<4));
      #pragma unroll
      for (int dt = 0; dt < 4; ++dt){
        b16x8 vf = *(const b16x8*)((const char*)vsh + (dt*16 + (lane&15))*432 + pt*64 + ((lane>>4)<<4));
        o[dt] = __builtin_amdgcn_mfma_f32_16x16x32_bf16(pa, vf, o[dt], 0, 0, 0);
      }
    }
    // tail p = 192..195 via shfl of reg-held P
    #pragma unroll
    for (int e = 0; e < 4; ++e){
      float pe[4];
      #pragma unroll
      for (int j = 0; j < 4; ++j) pe[j] = __shfl(pt12[j], (lane & 48) + e, 64);
      #pragma unroll
      for (int dt = 0; dt < 4; ++dt){
        b16 vv = *((const b16*)((const char*)vsh + (dt*16 + (lane&15))*432 + (192+e)*2));
        float vvf = (float)vv;
        #pragma unroll
        for (int j = 0; j < 4; ++j) o[dt][j] += pe[j]*vvf;
      }
    }
    // epilogue: av * PV + cv, scatter to O[b*196+n][h*64+d]
    #pragma unroll
    for (int dt = 0; dt < 4; ++dt)
      #pragma unroll
      for (int j = 0; j < 4; ++j){
        int n = n0 + ((lane>>4)<<2) + j;
        if (n < 196){
          long idx = ((long)(b*196 + n))*768 + h*64 + dt*16 + (lane&15);
          Ob[idx] = (b16)(av*o[dt][j] + cv);
        }
      }
  }
}

// ---------------------------------------------------------------- launch
extern "C" void kernel_launch(void* const* d_in, const int* in_sizes, int n_in,
                              void* d_out, int out_size, void* d_ws, size_t ws_size,
                              hipStream_t stream){
  const float* x         = (const float*)d_in[0];
  const float* W_qv      = (const float*)d_in[1];
  const float* k_ext     = (const float*)d_in[2];
  const float* attn_bias = (const float*)d_in[3];
  const float* bn_gamma  = (const float*)d_in[4];
  const float* bn_beta   = (const float*)d_in[5];
  const float* W_proj    = (const float*)d_in[6];
  const float* b_proj    = (const float*)d_in[7];
  float* out = (float*)d_out;

  char* ws = (char*)d_ws;
  const long SZ = 19267584;              // 9,633,792 bf16
  b16*   q_buf   = (b16*)(ws);
  b16*   v_buf   = (b16*)(ws + SZ);
  b16*   O_buf   = (b16*)(ws + 2*SZ);
  b16*   W_qvT   = (b16*)(ws + 3*SZ);                 // 2,359,296 B
  b16*   W_projT = (b16*)(ws + 3*SZ + 2359296);       // 1,179,648 B
  float* Kmat    = (float*)(ws + 3*SZ + 3538944);     // 16,384 B
  float* ksum    = Kmat + 4096;
  float* stats   = ksum + 64;
  float* coef    = stats + 48;

  hipMemsetAsync(stats, 0, 48*sizeof(float), stream);

  dim3 tb(32, 8);
  k_transpose_cvt<<<dim3(1536/32, 768/32), tb, 0, stream>>>(W_qv,   W_qvT,   768, 1536);
  k_transpose_cvt<<<dim3(768/32,  768/32), tb, 0, stream>>>(W_proj, W_projT, 768, 768);
  k_kprep<<<1, 256, 0, stream>>>(k_ext, Kmat, ksum);
  k_gemm<0><<<98*12, 256, 0, stream>>>(x, W_qvT, q_buf, v_buf, nullptr, nullptr);
  k_stats<<<1024, 256, 0, stream>>>(q_buf, v_buf, ksum, stats);
  k_qform<<<588, 256, 0, stream>>>(q_buf, Kmat, stats);
  k_final<<<1, 64, 0, stream>>>(stats, bn_gamma, bn_beta, coef);
  k_attn<<<768, 256, 0, stream>>>(q_buf, v_buf, k_ext, attn_bias, coef, O_buf);
  k_gemm<1><<<98*6, 256, 0, stream>>>(O_buf, W_projT, nullptr, nullptr, out, b_proj);
}

// Round 3
// 253.859 us; speedup vs baseline: 1.0958x; 1.0958x over previous
//
#include <hip/hip_runtime.h>
#include <hip/hip_bf16.h>

typedef __bf16 b16;
typedef __bf16 b16x8 __attribute__((ext_vector_type(8)));
typedef float  f32x4 __attribute__((ext_vector_type(4)));

#define B_   64
#define N_   196
#define C_   768
#define H_   12
#define HD_  64
#define TOK  (B_*N_)      // 12544
#define SCALE 0.125f

// async global->LDS, 16B per lane, wave-uniform LDS base
__device__ __forceinline__ void gl_lds16(const void* g, void* l){
  __builtin_amdgcn_global_load_lds((const __attribute__((address_space(1))) void*)g,
                                   (__attribute__((address_space(3))) void*)l, 16, 0, 0);
}

// ---------------------------------------------------------------- transpose+cvt
__global__ __launch_bounds__(256) void k_transpose_cvt(const float* __restrict__ in,
                                                       b16* __restrict__ out, int R, int C){
  __shared__ b16 tile[32][33];
  int tx = threadIdx.x, ty = threadIdx.y;
  int bx = blockIdx.x, by = blockIdx.y;
  int c = bx*32 + tx;
  #pragma unroll
  for (int i = 0; i < 32; i += 8){
    int r = by*32 + ty + i;
    tile[ty+i][tx] = (b16)in[(long)r*C + c];
  }
  __syncthreads();
  int rr = by*32 + tx;
  #pragma unroll
  for (int i = 0; i < 32; i += 8){
    int cc = bx*32 + ty + i;
    out[(long)cc*R + rr] = tile[tx][ty+i];
  }
}

// ---------------------------------------------------------------- x f32 -> bf16
__global__ __launch_bounds__(256) void k_cvt(const float* __restrict__ in, b16* __restrict__ out){
  long i = ((long)blockIdx.x*256 + threadIdx.x)*8;
  const float4* s = (const float4*)(in + i);
  float4 f0 = s[0], f1 = s[1];
  b16x8 v; v[0]=(b16)f0.x; v[1]=(b16)f0.y; v[2]=(b16)f0.z; v[3]=(b16)f0.w;
           v[4]=(b16)f1.x; v[5]=(b16)f1.y; v[6]=(b16)f1.z; v[7]=(b16)f1.w;
  *(b16x8*)(out + i) = v;
}

// ---------------------------------------------------------------- K = k^T k, ksum (4 blocks)
__global__ __launch_bounds__(256) void k_kprep(const float* __restrict__ k_ext,
                                               float* __restrict__ Kmat, float* __restrict__ ksum){
  __shared__ float ks[N_][HD_];
  int tid = threadIdx.x, blk = blockIdx.x;       // blk 0..3
  for (int i = tid; i < N_*HD_; i += 256) ks[i/HD_][i%HD_] = k_ext[i];
  __syncthreads();
  int i = tid >> 2;
  int j0 = blk*16 + (tid & 3)*4;
  float a0=0.f, a1=0.f, a2=0.f, a3=0.f;
  for (int p = 0; p < N_; ++p){
    float ki = ks[p][i];
    float4 kv = *(const float4*)&ks[p][j0];
    a0 += ki*kv.x; a1 += ki*kv.y; a2 += ki*kv.z; a3 += ki*kv.w;
  }
  Kmat[i*64+j0+0]=a0; Kmat[i*64+j0+1]=a1; Kmat[i*64+j0+2]=a2; Kmat[i*64+j0+3]=a3;
  if (blk == 0 && tid < 64){
    float s = 0.f;
    for (int p = 0; p < N_; ++p) s += ks[p][tid];
    ksum[tid] = s;
  }
}

// ---------------------------------------------------------------- tiled bf16 MFMA GEMM
// m97-style: global_load_lds(16B) staging, double-buffered LDS, 1 barrier/K-step.
// Pre-swizzled SOURCE + swizzled READ (rule #21): LDS dest stays linear.
// A [12544 x 768] bf16, BT [Ncols x 768] bf16 (pre-transposed weights).
// MODE0: scatter q/v bf16 [b,h,n,d]; MODE1: f32 out + bias
template<int MODE>
__global__ __launch_bounds__(256) void k_gemm(const b16* __restrict__ A,
                                              const b16* __restrict__ BT,
                                              b16* __restrict__ qout, b16* __restrict__ vout,
                                              float* __restrict__ fout, const float* __restrict__ bias){
  const int NT  = (MODE == 0) ? 12 : 6;
  const int NWG = 98*NT;
  // bijective XCD swizzle (m204)
  int orig = blockIdx.x;
  int q8 = NWG >> 3, r8 = NWG & 7;
  int xcd = orig & 7, loc = orig >> 3;
  int bid = (xcd < r8 ? xcd*(q8+1) : r8*(q8+1) + (xcd-r8)*q8) + loc;
  int rt = bid / NT, ct = bid % NT;
  int brow = rt*128, bcol = ct*128;

  __shared__ b16 sm[2][2][128*32];   // [buf][A/B], 32 KiB total
  int tid = threadIdx.x, lane = tid & 63, w = tid >> 6;
  int wr = w >> 1, wc = w & 1;

  // staging addresses: lane covers row rsub=(w*16+(lane>>2)), group gsrc (source pre-swizzle)
  int rsub = w*16 + (lane>>2);
  int gsrc = (lane & 3) ^ ((lane >> 3) & 3);
  const b16* gA = A  + (long)(brow + rsub)*768 + gsrc*8;
  const b16* gB = BT + (long)(bcol + rsub)*768 + gsrc*8;
  b16* lA0 = &sm[0][0][w*16*32];
  b16* lB0 = &sm[0][1][w*16*32];
  b16* lA1 = &sm[1][0][w*16*32];
  b16* lB1 = &sm[1][1][w*16*32];

#define STAGE(la, lb, kt) do{ \
    gl_lds16(gA + (kt)*32,            (la));        \
    gl_lds16(gA + (kt)*32 + 64*768,   (la) + 64*32);\
    gl_lds16(gB + (kt)*32,            (lb));        \
    gl_lds16(gB + (kt)*32 + 64*768,   (lb) + 64*32);\
  } while(0)

  f32x4 acc[4][4];
  #pragma unroll
  for (int m = 0; m < 4; ++m)
    #pragma unroll
    for (int n = 0; n < 4; ++n) acc[m][n] = (f32x4){0.f,0.f,0.f,0.f};

  STAGE(lA0, lB0, 0);
  __syncthreads();

  #pragma unroll 2
  for (int kt = 0; kt < 24; ++kt){
    int cur = kt & 1;
    if (kt < 23){
      if (cur) STAGE(lA0, lB0, kt+1);
      else     STAGE(lA1, lB1, kt+1);
    }
    const char* smA = (const char*)sm[cur][0];
    const char* smB = (const char*)sm[cur][1];
    b16x8 af[4], bf[4];
    #pragma unroll
    for (int m = 0; m < 4; ++m){
      int row = wr*64 + m*16 + (lane & 15);
      af[m] = *(const b16x8*)(smA + row*64 + (((lane>>4) ^ ((row>>1)&3))<<4));
    }
    #pragma unroll
    for (int n = 0; n < 4; ++n){
      int row = wc*64 + n*16 + (lane & 15);
      bf[n] = *(const b16x8*)(smB + row*64 + (((lane>>4) ^ ((row>>1)&3))<<4));
    }
    #pragma unroll
    for (int m = 0; m < 4; ++m)
      #pragma unroll
      for (int n = 0; n < 4; ++n)
        acc[m][n] = __builtin_amdgcn_mfma_f32_16x16x32_bf16(af[m], bf[n], acc[m][n], 0, 0, 0);
    __syncthreads();   // drains vmcnt (next tile arrived) + frees cur buffer
  }
#undef STAGE

  if constexpr (MODE == 0){
    #pragma unroll
    for (int m = 0; m < 4; ++m){
      #pragma unroll
      for (int n = 0; n < 4; ++n){
        int col = bcol + wc*64 + n*16 + (lane & 15);
        int two = (col >= 768) ? 1 : 0;
        int hc = col - two*768;
        int hh = hc >> 6, d = hc & 63;
        b16* dst = two ? vout : qout;
        #pragma unroll
        for (int j = 0; j < 4; ++j){
          int r2 = brow + wr*64 + m*16 + ((lane>>4)<<2) + j;
          int bq = r2 / 196;
          int nn = r2 - bq*196;
          dst[((bq*12 + hh)*196 + nn)*64 + d] = (b16)acc[m][n][j];
        }
      }
    }
  } else {
    #pragma unroll
    for (int m = 0; m < 4; ++m){
      #pragma unroll
      for (int n = 0; n < 4; ++n){
        int col = bcol + wc*64 + n*16 + (lane & 15);
        float bv = bias[col];
        #pragma unroll
        for (int j = 0; j < 4; ++j){
          int r2 = brow + wr*64 + m*16 + ((lane>>4)<<2) + j;
          fout[(long)r2*768 + col] = acc[m][n][j] + bv;
        }
      }
    }
  }
}

// ---------------------------------------------------------------- fused q*ksum + v stats
__global__ __launch_bounds__(256) void k_stats(const b16* __restrict__ q, const b16* __restrict__ v,
                                               const float* __restrict__ ksum, float* __restrict__ stats){
  __shared__ float ksh[64];
  __shared__ float bins[12][3];
  int tid = threadIdx.x;
  if (tid < 64) ksh[tid] = ksum[tid];
  if (tid < 36) ((float*)bins)[tid] = 0.f;
  __syncthreads();
  const long NCH = (long)9633792/8;
  for (long i = (long)blockIdx.x*256 + tid; i < NCH; i += (long)gridDim.x*256){
    long e0 = i*8;
    int head = (int)(e0 / (196*64)) % 12;
    b16x8 q8 = *(const b16x8*)(q + e0);
    b16x8 v8 = *(const b16x8*)(v + e0);
    int d0 = (int)(e0 & 63);
    float s1 = 0.f, vs = 0.f, vs2 = 0.f;
    #pragma unroll
    for (int j = 0; j < 8; ++j){
      float qf = (float)q8[j], vf = (float)v8[j];
      s1 += qf*ksh[d0+j]; vs += vf; vs2 += vf*vf;
    }
    atomicAdd(&bins[head][0], s1);
    atomicAdd(&bins[head][1], vs);
    atomicAdd(&bins[head][2], vs2);
  }
  __syncthreads();
  if (tid < 12){
    atomicAdd(&stats[tid],      bins[tid][0]);
    atomicAdd(&stats[24+tid],   bins[tid][1]);
    atomicAdd(&stats[36+tid],   bins[tid][2]);
  }
}

// ---------------------------------------------------------------- S2 = sum q^T K q per head
__global__ __launch_bounds__(256) void k_qform(const b16* __restrict__ q,
                                               const float* __restrict__ Kmat,
                                               float* __restrict__ stats){
  __shared__ float bins[12];
  int tid = threadIdx.x;
  if (tid < 12) bins[tid] = 0.f;
  __syncthreads();
  long token = (long)blockIdx.x*256 + tid;
  float qr[64];
  const b16x8* qp = (const b16x8*)(q + token*64);
  #pragma unroll
  for (int j = 0; j < 8; ++j){
    b16x8 t = qp[j];
    #pragma unroll
    for (int e = 0; e < 8; ++e) qr[j*8+e] = (float)t[e];
  }
  float s2 = 0.f;
  #pragma unroll
  for (int i2 = 0; i2 < 64; ++i2){
    const float4* kr = (const float4*)(Kmat + i2*64);
    float a = 0.f;
    #pragma unroll
    for (int j4 = 0; j4 < 16; ++j4){
      float4 kv = kr[j4];
      a += kv.x*qr[j4*4] + kv.y*qr[j4*4+1] + kv.z*qr[j4*4+2] + kv.w*qr[j4*4+3];
    }
    s2 += a * qr[i2];
  }
  int head = (int)(token / 196) % 12;
  atomicAdd(&bins[head], s2);
  __syncthreads();
  if (tid < 12) atomicAdd(&stats[12+tid], bins[tid]);
}

// ---------------------------------------------------------------- finalize per-head coefs
__global__ void k_final(const float* __restrict__ stats, const float* __restrict__ gamma,
                        const float* __restrict__ beta, float* __restrict__ coef){
  int h = threadIdx.x;
  if (h < 12){
    const float cntS = 2458624.f, cntV = 802816.f;
    float S1 = stats[h], S2 = stats[12+h], VS = stats[24+h], VS2 = stats[36+h];
    float ms = S1/cntS;
    float vars = S2/cntS - ms*ms;
    float alpha = gamma[h]*SCALE*rsqrtf(vars + 1e-5f);
    float mv = VS/cntV;
    float varv = VS2/cntV - mv*mv;
    float a = gamma[h]*rsqrtf(varv + 1e-5f);
    coef[h*4+0] = alpha;
    coef[h*4+1] = a;
    coef[h*4+2] = beta[h] - a*mv;
  }
}

// ---------------------------------------------------------------- fused attention per (b,h)
__global__ __launch_bounds__(256, 2) void k_attn(const b16* __restrict__ qb, const b16* __restrict__ vb,
                                                 const float* __restrict__ k_ext,
                                                 const float* __restrict__ attn_bias,
                                                 const float* __restrict__ coef,
                                                 b16* __restrict__ Ob){
  __shared__ b16 ksh[196*64];
  __shared__ b16 vsh[64*216];
  __shared__ b16 psh[4][16*200];
  __shared__ float bsh[196];

  int tid = threadIdx.x, lane = tid & 63, wid = tid >> 6;
  int bh = blockIdx.x;
  int h = bh % 12, b = bh / 12;
  const b16* qt = qb + (long)bh*N_*64;
  const b16* vt = vb + (long)bh*N_*64;
  float alpha = coef[h*4+0], av = coef[h*4+1], cv = coef[h*4+2];

  for (int c = tid; c < 196*8; c += 256){
    int p = c >> 3, g = c & 7;
    const float4* src = (const float4*)(k_ext + p*64 + g*8);
    float4 f0 = src[0], f1 = src[1];
    b16x8 v; v[0]=(b16)f0.x; v[1]=(b16)f0.y; v[2]=(b16)f0.z; v[3]=(b16)f0.w;
             v[4]=(b16)f1.x; v[5]=(b16)f1.y; v[6]=(b16)f1.z; v[7]=(b16)f1.w;
    *(b16x8*)((char*)ksh + p*128 + ((g ^ (p&7))<<4)) = v;
  }
  for (int p = tid; p < 196; p += 256) bsh[p] = attn_bias[p]*SCALE;
  {
    int d = tid & 63;
    for (int p0 = (tid>>6)*8; p0 < 196; p0 += 32){
      b16x8 w;
      #pragma unroll
      for (int j = 0; j < 8; ++j){
        int p = p0 + j;
        w[j] = (p < 196) ? vt[p*64 + d] : (b16)0.f;
      }
      *(b16x8*)((char*)vsh + d*432 + p0*2) = w;
    }
  }
  __syncthreads();

  for (int rt = wid; rt < 13; rt += 4){
    int n0 = rt*16;
    int qrow = n0 + (lane & 15); if (qrow > 195) qrow = 195;
    b16x8 a0 = *(const b16x8*)((const char*)qt + qrow*128 +      ((lane>>4)<<4));
    b16x8 a1 = *(const b16x8*)((const char*)qt + qrow*128 + 64 + ((lane>>4)<<4));

    f32x4 sc[13];
    #pragma unroll
    for (int ct = 0; ct < 13; ++ct){
      int p = ct*16 + (lane & 15); int pc = p > 195 ? 195 : p;
      b16x8 b0 = *(const b16x8*)((const char*)ksh + pc*128 + ((( (lane>>4))   ^ (pc&7))<<4));
      b16x8 b1 = *(const b16x8*)((const char*)ksh + pc*128 + (((4+(lane>>4))  ^ (pc&7))<<4));
      f32x4 z = {0.f,0.f,0.f,0.f};
      z = __builtin_amdgcn_mfma_f32_16x16x32_bf16(a0, b0, z, 0, 0, 0);
      z = __builtin_amdgcn_mfma_f32_16x16x32_bf16(a1, b1, z, 0, 0, 0);
      sc[ct] = z;
    }
    int pcol = lane & 15;
    float mx[4] = {-1e30f,-1e30f,-1e30f,-1e30f};
    #pragma unroll
    for (int ct = 0; ct < 13; ++ct){
      int p = ct*16 + pcol;
      bool valid = (p < 196);
      float badd = valid ? bsh[p < 196 ? p : 0] : 0.f;
      #pragma unroll
      for (int j = 0; j < 4; ++j){
        float lv = valid ? (sc[ct][j]*alpha + badd) : -1e30f;
        sc[ct][j] = lv;
        mx[j] = fmaxf(mx[j], lv);
      }
    }
    #pragma unroll
    for (int off = 1; off < 16; off <<= 1)
      #pragma unroll
      for (int j = 0; j < 4; ++j) mx[j] = fmaxf(mx[j], __shfl_xor(mx[j], off, 64));
    float sm[4] = {0.f,0.f,0.f,0.f};
    #pragma unroll
    for (int ct = 0; ct < 13; ++ct)
      #pragma unroll
      for (int j = 0; j < 4; ++j){
        float e = __expf(sc[ct][j] - mx[j]);
        sc[ct][j] = e; sm[j] += e;
      }
    #pragma unroll
    for (int off = 1; off < 16; off <<= 1)
      #pragma unroll
      for (int j = 0; j < 4; ++j) sm[j] += __shfl_xor(sm[j], off, 64);
    float rs[4];
    #pragma unroll
    for (int j = 0; j < 4; ++j) rs[j] = 1.f/sm[j];

    b16* pw = psh[wid];
    #pragma unroll
    for (int ct = 0; ct < 12; ++ct){
      int p = ct*16 + pcol;
      #pragma unroll
      for (int j = 0; j < 4; ++j){
        int r = ((lane>>4)<<2) + j;
        pw[r*200 + p] = (b16)(sc[ct][j]*rs[j]);
      }
    }
    float pt12[4];
    #pragma unroll
    for (int j = 0; j < 4; ++j) pt12[j] = sc[12][j]*rs[j];

    __asm__ volatile("s_waitcnt lgkmcnt(0)" ::: "memory");
    __builtin_amdgcn_sched_barrier(0);

    f32x4 o[4];
    #pragma unroll
    for (int dt = 0; dt < 4; ++dt) o[dt] = (f32x4){0.f,0.f,0.f,0.f};
    #pragma unroll
    for (int pt = 0; pt < 6; ++pt){
      b16x8 pa = *(const b16x8*)((const char*)pw + (lane&15)*400 + pt*64 + ((lane>>4)<<4));
      #pragma unroll
      for (int dt = 0; dt < 4; ++dt){
        b16x8 vf = *(const b16x8*)((const char*)vsh + (dt*16 + (lane&15))*432 + pt*64 + ((lane>>4)<<4));
        o[dt] = __builtin_amdgcn_mfma_f32_16x16x32_bf16(pa, vf, o[dt], 0, 0, 0);
      }
    }
    #pragma unroll
    for (int e = 0; e < 4; ++e){
      float pe[4];
      #pragma unroll
      for (int j = 0; j < 4; ++j) pe[j] = __shfl(pt12[j], (lane & 48) + e, 64);
      #pragma unroll
      for (int dt = 0; dt < 4; ++dt){
        b16 vv = *((const b16*)((const char*)vsh + (dt*16 + (lane&15))*432 + (192+e)*2));
        float vvf = (float)vv;
        #pragma unroll
        for (int j = 0; j < 4; ++j) o[dt][j] += pe[j]*vvf;
      }
    }
    #pragma unroll
    for (int dt = 0; dt < 4; ++dt)
      #pragma unroll
      for (int j = 0; j < 4; ++j){
        int n = n0 + ((lane>>4)<<2) + j;
        if (n < 196){
          long idx = ((long)(b*196 + n))*768 + h*64 + dt*16 + (lane&15);
          Ob[idx] = (b16)(av*o[dt][j] + cv);
        }
      }
  }
}

// ---------------------------------------------------------------- launch
extern "C" void kernel_launch(void* const* d_in, const int* in_sizes, int n_in,
                              void* d_out, int out_size, void* d_ws, size_t ws_size,
                              hipStream_t stream){
  const float* x         = (const float*)d_in[0];
  const float* W_qv      = (const float*)d_in[1];
  const float* k_ext     = (const float*)d_in[2];
  const float* attn_bias = (const float*)d_in[3];
  const float* bn_gamma  = (const float*)d_in[4];
  const float* bn_beta   = (const float*)d_in[5];
  const float* W_proj    = (const float*)d_in[6];
  const float* b_proj    = (const float*)d_in[7];
  float* out = (float*)d_out;

  char* ws = (char*)d_ws;
  const long SZ = 19267584;              // 9,633,792 bf16
  b16*   q_buf   = (b16*)(ws);
  b16*   v_buf   = (b16*)(ws + SZ);
  b16*   O_buf   = (b16*)(ws + 2*SZ);    // doubles as x_bf16 before k_attn
  b16*   x_bf16  = (b16*)(ws + 2*SZ);
  b16*   W_qvT   = (b16*)(ws + 3*SZ);
  b16*   W_projT = (b16*)(ws + 3*SZ + 2359296);
  float* Kmat    = (float*)(ws + 3*SZ + 3538944);
  float* ksum    = Kmat + 4096;
  float* stats   = ksum + 64;
  float* coef    = stats + 48;

  hipMemsetAsync(stats, 0, 48*sizeof(float), stream);

  dim3 tb(32, 8);
  k_transpose_cvt<<<dim3(1536/32, 768/32), tb, 0, stream>>>(W_qv,   W_qvT,   768, 1536);
  k_transpose_cvt<<<dim3(768/32,  768/32), tb, 0, stream>>>(W_proj, W_projT, 768, 768);
  k_cvt<<<4704, 256, 0, stream>>>(x, x_bf16);
  k_kprep<<<4, 256, 0, stream>>>(k_ext, Kmat, ksum);
  k_gemm<0><<<98*12, 256, 0, stream>>>(x_bf16, W_qvT, q_buf, v_buf, nullptr, nullptr);
  k_stats<<<1024, 256, 0, stream>>>(q_buf, v_buf, ksum, stats);
  k_qform<<<588, 256, 0, stream>>>(q_buf, Kmat, stats);
  k_final<<<1, 64, 0, stream>>>(stats, bn_gamma, bn_beta, coef);
  k_attn<<<768, 256, 0, stream>>>(q_buf, v_buf, k_ext, attn_bias, coef, O_buf);
  k_gemm<1><<<98*6, 256, 0, stream>>>(O_buf, W_projT, nullptr, nullptr, out, b_proj);
}

// Round 4
// 199.722 us; speedup vs baseline: 1.3928x; 1.2711x over previous
//
#include <hip/hip_runtime.h>
#include <hip/hip_bf16.h>

typedef __bf16 b16;
typedef __bf16 b16x8 __attribute__((ext_vector_type(8)));
typedef float  f32x4 __attribute__((ext_vector_type(4)));

#define B_   64
#define N_   196
#define C_   768
#define H_   12
#define HD_  64
#define TOK  (B_*N_)      // 12544
#define SCALE 0.125f

// async global->LDS, 16B per lane, wave-uniform LDS base
__device__ __forceinline__ void gl_lds16(const void* g, void* l){
  __builtin_amdgcn_global_load_lds((const __attribute__((address_space(1))) void*)g,
                                   (__attribute__((address_space(3))) void*)l, 16, 0, 0);
}

// ---------------------------------------------------------------- transpose+cvt
__global__ __launch_bounds__(256) void k_transpose_cvt(const float* __restrict__ in,
                                                       b16* __restrict__ out, int R, int C){
  __shared__ b16 tile[32][33];
  int tx = threadIdx.x, ty = threadIdx.y;
  int bx = blockIdx.x, by = blockIdx.y;
  int c = bx*32 + tx;
  #pragma unroll
  for (int i = 0; i < 32; i += 8){
    int r = by*32 + ty + i;
    tile[ty+i][tx] = (b16)in[(long)r*C + c];
  }
  __syncthreads();
  int rr = by*32 + tx;
  #pragma unroll
  for (int i = 0; i < 32; i += 8){
    int cc = bx*32 + ty + i;
    out[(long)cc*R + rr] = tile[tx][ty+i];
  }
}

// ---------------------------------------------------------------- x f32 -> bf16
__global__ __launch_bounds__(256) void k_cvt(const float* __restrict__ in, b16* __restrict__ out){
  long i = ((long)blockIdx.x*256 + threadIdx.x)*8;
  const float4* s = (const float4*)(in + i);
  float4 f0 = s[0], f1 = s[1];
  b16x8 v; v[0]=(b16)f0.x; v[1]=(b16)f0.y; v[2]=(b16)f0.z; v[3]=(b16)f0.w;
           v[4]=(b16)f1.x; v[5]=(b16)f1.y; v[6]=(b16)f1.z; v[7]=(b16)f1.w;
  *(b16x8*)(out + i) = v;
}

// ---------------------------------------------------------------- K = k^T k, ksum (4 blocks)
__global__ __launch_bounds__(256) void k_kprep(const float* __restrict__ k_ext,
                                               float* __restrict__ Kmat, float* __restrict__ ksum){
  __shared__ float ks[N_][HD_];
  int tid = threadIdx.x, blk = blockIdx.x;       // blk 0..3
  for (int i = tid; i < N_*HD_; i += 256) ks[i/HD_][i%HD_] = k_ext[i];
  __syncthreads();
  int i = tid >> 2;
  int j0 = blk*16 + (tid & 3)*4;
  float a0=0.f, a1=0.f, a2=0.f, a3=0.f;
  for (int p = 0; p < N_; ++p){
    float ki = ks[p][i];
    float4 kv = *(const float4*)&ks[p][j0];
    a0 += ki*kv.x; a1 += ki*kv.y; a2 += ki*kv.z; a3 += ki*kv.w;
  }
  Kmat[i*64+j0+0]=a0; Kmat[i*64+j0+1]=a1; Kmat[i*64+j0+2]=a2; Kmat[i*64+j0+3]=a3;
  if (blk == 0 && tid < 64){
    float s = 0.f;
    for (int p = 0; p < N_; ++p) s += ks[p][tid];
    ksum[tid] = s;
  }
}

// ---------------------------------------------------------------- tiled bf16 MFMA GEMM
// global_load_lds(16B) staging, double-buffered LDS, pre-swizzled source + swizzled read.
// MODE0: scatter q/v bf16 [b,h,n,d] + fused BN stats (S1, Vsum, Vsum2); MODE1: f32 out + bias
template<int MODE>
__global__ __launch_bounds__(256) void k_gemm(const b16* __restrict__ A,
                                              const b16* __restrict__ BT,
                                              b16* __restrict__ qout, b16* __restrict__ vout,
                                              float* __restrict__ fout, const float* __restrict__ bias,
                                              const float* __restrict__ ksum, float* __restrict__ stats){
  const int NT  = (MODE == 0) ? 12 : 6;
  const int NWG = 98*NT;
  // bijective XCD swizzle (m204)
  int orig = blockIdx.x;
  int q8 = NWG >> 3, r8 = NWG & 7;
  int xcd = orig & 7, loc = orig >> 3;
  int bid = (xcd < r8 ? xcd*(q8+1) : r8*(q8+1) + (xcd-r8)*q8) + loc;
  int rt = bid / NT, ct = bid % NT;
  int brow = rt*128, bcol = ct*128;

  __shared__ b16 sm[2][2][128*32];   // [buf][A/B], 32 KiB
  __shared__ float ksh[64];
  int tid = threadIdx.x, lane = tid & 63, w = tid >> 6;
  int wr = w >> 1, wc = w & 1;
  if constexpr (MODE == 0){ if (tid < 64) ksh[tid] = ksum[tid]; }

  int rsub = w*16 + (lane>>2);
  int gsrc = (lane & 3) ^ ((lane >> 3) & 3);
  const b16* gA = A  + (long)(brow + rsub)*768 + gsrc*8;
  const b16* gB = BT + (long)(bcol + rsub)*768 + gsrc*8;
  b16* lA0 = &sm[0][0][w*16*32];
  b16* lB0 = &sm[0][1][w*16*32];
  b16* lA1 = &sm[1][0][w*16*32];
  b16* lB1 = &sm[1][1][w*16*32];

#define STAGE(la, lb, kt) do{ \
    gl_lds16(gA + (kt)*32,            (la));        \
    gl_lds16(gA + (kt)*32 + 64*768,   (la) + 64*32);\
    gl_lds16(gB + (kt)*32,            (lb));        \
    gl_lds16(gB + (kt)*32 + 64*768,   (lb) + 64*32);\
  } while(0)

  f32x4 acc[4][4];
  #pragma unroll
  for (int m = 0; m < 4; ++m)
    #pragma unroll
    for (int n = 0; n < 4; ++n) acc[m][n] = (f32x4){0.f,0.f,0.f,0.f};

  STAGE(lA0, lB0, 0);
  __syncthreads();

  #pragma unroll 2
  for (int kt = 0; kt < 24; ++kt){
    int cur = kt & 1;
    if (kt < 23){
      if (cur) STAGE(lA0, lB0, kt+1);
      else     STAGE(lA1, lB1, kt+1);
    }
    const char* smA = (const char*)sm[cur][0];
    const char* smB = (const char*)sm[cur][1];
    b16x8 af[4], bf[4];
    #pragma unroll
    for (int m = 0; m < 4; ++m){
      int row = wr*64 + m*16 + (lane & 15);
      af[m] = *(const b16x8*)(smA + row*64 + (((lane>>4) ^ ((row>>1)&3))<<4));
    }
    #pragma unroll
    for (int n = 0; n < 4; ++n){
      int row = wc*64 + n*16 + (lane & 15);
      bf[n] = *(const b16x8*)(smB + row*64 + (((lane>>4) ^ ((row>>1)&3))<<4));
    }
    #pragma unroll
    for (int m = 0; m < 4; ++m)
      #pragma unroll
      for (int n = 0; n < 4; ++n)
        acc[m][n] = __builtin_amdgcn_mfma_f32_16x16x32_bf16(af[m], bf[n], acc[m][n], 0, 0, 0);
    __syncthreads();
  }
#undef STAGE

  if constexpr (MODE == 0){
    #pragma unroll
    for (int m = 0; m < 4; ++m){
      #pragma unroll
      for (int n = 0; n < 4; ++n){
        int col = bcol + wc*64 + n*16 + (lane & 15);
        int two = (col >= 768) ? 1 : 0;
        int hc = col - two*768;
        int hh = hc >> 6, d = hc & 63;
        b16* dst = two ? vout : qout;
        #pragma unroll
        for (int j = 0; j < 4; ++j){
          int r2 = brow + wr*64 + m*16 + ((lane>>4)<<2) + j;
          int bq = r2 / 196;
          int nn = r2 - bq*196;
          dst[((bq*12 + hh)*196 + nn)*64 + d] = (b16)acc[m][n][j];
        }
      }
    }
    // fused BN stats: per wave all cols belong to ONE head
    {
      bool isV = (bcol >= 768);
      float a_acc = 0.f, b_acc = 0.f;
      #pragma unroll
      for (int n = 0; n < 4; ++n){
        int d = n*16 + (lane & 15);
        float s = 0.f, s2 = 0.f;
        #pragma unroll
        for (int m = 0; m < 4; ++m)
          #pragma unroll
          for (int j = 0; j < 4; ++j){
            float v = acc[m][n][j];
            s += v; s2 += v*v;
          }
        if (isV){ a_acc += s; b_acc += s2; }
        else      a_acc += s * ksh[d];
      }
      #pragma unroll
      for (int off = 1; off < 64; off <<= 1){
        a_acc += __shfl_xor(a_acc, off, 64);
        b_acc += __shfl_xor(b_acc, off, 64);
      }
      if (lane == 0){
        if (isV){
          int hv = 2*(ct - 6) + wc;
          atomicAdd(&stats[24 + hv], a_acc);
          atomicAdd(&stats[36 + hv], b_acc);
        } else {
          int hq = 2*ct + wc;
          atomicAdd(&stats[hq], a_acc);
        }
      }
    }
  } else {
    #pragma unroll
    for (int m = 0; m < 4; ++m){
      #pragma unroll
      for (int n = 0; n < 4; ++n){
        int col = bcol + wc*64 + n*16 + (lane & 15);
        float bv = bias[col];
        #pragma unroll
        for (int j = 0; j < 4; ++j){
          int r2 = brow + wr*64 + m*16 + ((lane>>4)<<2) + j;
          fout[(long)r2*768 + col] = acc[m][n][j] + bv;
        }
      }
    }
  }
}

// ---------------------------------------------------------------- per-head Gram G = sum_t q q^T (MFMA)
// block = (head, pair of batches); acc persists across the 2 rounds; atomicAdd into G[h]
__global__ __launch_bounds__(256) void k_gram(const b16* __restrict__ qb, float* __restrict__ G){
  __shared__ b16 qT[64*232];          // [d][t] stride 232 (bank-balanced per quarter-wave)
  int tid = threadIdx.x, lane = tid & 63, w = tid >> 6;
  int h = blockIdx.x % 12, bg = blockIdx.x / 12;   // bg 0..31
  f32x4 acc[4];
  #pragma unroll
  for (int n = 0; n < 4; ++n) acc[n] = (f32x4){0.f,0.f,0.f,0.f};
  #pragma unroll 1
  for (int r = 0; r < 2; ++r){
    int b = bg*2 + r;
    const b16* src = qb + ((long)(b*12 + h))*196*64;
    int d = lane;
    for (int p0 = w*8; p0 < 224; p0 += 32){
      b16x8 w8;
      #pragma unroll
      for (int j = 0; j < 8; ++j){
        int p = p0 + j;
        w8[j] = (p < 196) ? src[p*64 + d] : (b16)0.f;
      }
      *(b16x8*)(qT + d*232 + p0) = w8;
    }
    __syncthreads();
    #pragma unroll
    for (int ks = 0; ks < 7; ++ks){
      int t0 = ks*32;
      b16x8 af = *(const b16x8*)(qT + (16*w + (lane&15))*232 + t0 + ((lane>>4)<<3));
      #pragma unroll
      for (int n = 0; n < 4; ++n){
        b16x8 bf = *(const b16x8*)(qT + (16*n + (lane&15))*232 + t0 + ((lane>>4)<<3));
        acc[n] = __builtin_amdgcn_mfma_f32_16x16x32_bf16(af, bf, acc[n], 0, 0, 0);
      }
    }
    __syncthreads();
  }
  float* Gh = G + h*4096;
  #pragma unroll
  for (int n = 0; n < 4; ++n)
    #pragma unroll
    for (int j = 0; j < 4; ++j){
      int i  = 16*w + ((lane>>4)<<2) + j;
      int jj = 16*n + (lane&15);
      atomicAdd(&Gh[i*64 + jj], acc[n][j]);
    }
}

// ---------------------------------------------------------------- S2 = <G,K>, finalize coefs
__global__ __launch_bounds__(256) void k_sfin(const float* __restrict__ G, const float* __restrict__ Kmat,
                                              const float* __restrict__ stats, const float* __restrict__ gamma,
                                              const float* __restrict__ beta, float* __restrict__ coef){
  int h = blockIdx.x, tid = threadIdx.x;
  const float* Gh = G + h*4096;
  float s = 0.f;
  #pragma unroll
  for (int k = 0; k < 16; ++k) s += Gh[tid + k*256]*Kmat[tid + k*256];
  #pragma unroll
  for (int off = 1; off < 64; off <<= 1) s += __shfl_xor(s, off, 64);
  __shared__ float red[4];
  if ((tid & 63) == 0) red[tid>>6] = s;
  __syncthreads();
  if (tid == 0){
    float S2 = red[0]+red[1]+red[2]+red[3];
    const float cntS = 2458624.f, cntV = 802816.f;
    float S1 = stats[h], VS = stats[24+h], VS2 = stats[36+h];
    float ms = S1/cntS;
    float vars = S2/cntS - ms*ms;
    float alpha = gamma[h]*SCALE*rsqrtf(vars + 1e-5f);
    float mv = VS/cntV;
    float varv = VS2/cntV - mv*mv;
    float a = gamma[h]*rsqrtf(varv + 1e-5f);
    coef[h*4+0] = alpha;
    coef[h*4+1] = a;
    coef[h*4+2] = beta[h] - a*mv;
  }
}

// ---------------------------------------------------------------- fused attention per (b,h)
__global__ __launch_bounds__(256, 2) void k_attn(const b16* __restrict__ qb, const b16* __restrict__ vb,
                                                 const float* __restrict__ k_ext,
                                                 const float* __restrict__ attn_bias,
                                                 const float* __restrict__ coef,
                                                 b16* __restrict__ Ob){
  __shared__ b16 ksh[196*64];
  __shared__ b16 vsh[64*216];
  __shared__ b16 psh[4][16*200];
  __shared__ float bsh[196];

  int tid = threadIdx.x, lane = tid & 63, wid = tid >> 6;
  int bh = blockIdx.x;
  int h = bh % 12, b = bh / 12;
  const b16* qt = qb + (long)bh*N_*64;
  const b16* vt = vb + (long)bh*N_*64;
  float alpha = coef[h*4+0], av = coef[h*4+1], cv = coef[h*4+2];

  for (int c = tid; c < 196*8; c += 256){
    int p = c >> 3, g = c & 7;
    const float4* src = (const float4*)(k_ext + p*64 + g*8);
    float4 f0 = src[0], f1 = src[1];
    b16x8 v; v[0]=(b16)f0.x; v[1]=(b16)f0.y; v[2]=(b16)f0.z; v[3]=(b16)f0.w;
             v[4]=(b16)f1.x; v[5]=(b16)f1.y; v[6]=(b16)f1.z; v[7]=(b16)f1.w;
    *(b16x8*)((char*)ksh + p*128 + ((g ^ (p&7))<<4)) = v;
  }
  for (int p = tid; p < 196; p += 256) bsh[p] = attn_bias[p]*SCALE;
  {
    int d = tid & 63;
    for (int p0 = (tid>>6)*8; p0 < 196; p0 += 32){
      b16x8 w;
      #pragma unroll
      for (int j = 0; j < 8; ++j){
        int p = p0 + j;
        w[j] = (p < 196) ? vt[p*64 + d] : (b16)0.f;
      }
      *(b16x8*)((char*)vsh + d*432 + p0*2) = w;
    }
  }
  __syncthreads();

  for (int rt = wid; rt < 13; rt += 4){
    int n0 = rt*16;
    int qrow = n0 + (lane & 15); if (qrow > 195) qrow = 195;
    b16x8 a0 = *(const b16x8*)((const char*)qt + qrow*128 +      ((lane>>4)<<4));
    b16x8 a1 = *(const b16x8*)((const char*)qt + qrow*128 + 64 + ((lane>>4)<<4));

    f32x4 sc[13];
    #pragma unroll
    for (int ct = 0; ct < 13; ++ct){
      int p = ct*16 + (lane & 15); int pc = p > 195 ? 195 : p;
      b16x8 b0 = *(const b16x8*)((const char*)ksh + pc*128 + ((( (lane>>4))   ^ (pc&7))<<4));
      b16x8 b1 = *(const b16x8*)((const char*)ksh + pc*128 + (((4+(lane>>4))  ^ (pc&7))<<4));
      f32x4 z = {0.f,0.f,0.f,0.f};
      z = __builtin_amdgcn_mfma_f32_16x16x32_bf16(a0, b0, z, 0, 0, 0);
      z = __builtin_amdgcn_mfma_f32_16x16x32_bf16(a1, b1, z, 0, 0, 0);
      sc[ct] = z;
    }
    int pcol = lane & 15;
    float mx[4] = {-1e30f,-1e30f,-1e30f,-1e30f};
    #pragma unroll
    for (int ct = 0; ct < 13; ++ct){
      int p = ct*16 + pcol;
      bool valid = (p < 196);
      float badd = valid ? bsh[p < 196 ? p : 0] : 0.f;
      #pragma unroll
      for (int j = 0; j < 4; ++j){
        float lv = valid ? (sc[ct][j]*alpha + badd) : -1e30f;
        sc[ct][j] = lv;
        mx[j] = fmaxf(mx[j], lv);
      }
    }
    #pragma unroll
    for (int off = 1; off < 16; off <<= 1)
      #pragma unroll
      for (int j = 0; j < 4; ++j) mx[j] = fmaxf(mx[j], __shfl_xor(mx[j], off, 64));
    float sm[4] = {0.f,0.f,0.f,0.f};
    #pragma unroll
    for (int ct = 0; ct < 13; ++ct)
      #pragma unroll
      for (int j = 0; j < 4; ++j){
        float e = __expf(sc[ct][j] - mx[j]);
        sc[ct][j] = e; sm[j] += e;
      }
    #pragma unroll
    for (int off = 1; off < 16; off <<= 1)
      #pragma unroll
      for (int j = 0; j < 4; ++j) sm[j] += __shfl_xor(sm[j], off, 64);
    float rs[4];
    #pragma unroll
    for (int j = 0; j < 4; ++j) rs[j] = 1.f/sm[j];

    b16* pw = psh[wid];
    #pragma unroll
    for (int ct = 0; ct < 12; ++ct){
      int p = ct*16 + pcol;
      #pragma unroll
      for (int j = 0; j < 4; ++j){
        int r = ((lane>>4)<<2) + j;
        pw[r*200 + p] = (b16)(sc[ct][j]*rs[j]);
      }
    }
    float pt12[4];
    #pragma unroll
    for (int j = 0; j < 4; ++j) pt12[j] = sc[12][j]*rs[j];

    __asm__ volatile("s_waitcnt lgkmcnt(0)" ::: "memory");
    __builtin_amdgcn_sched_barrier(0);

    f32x4 o[4];
    #pragma unroll
    for (int dt = 0; dt < 4; ++dt) o[dt] = (f32x4){0.f,0.f,0.f,0.f};
    #pragma unroll
    for (int pt = 0; pt < 6; ++pt){
      b16x8 pa = *(const b16x8*)((const char*)pw + (lane&15)*400 + pt*64 + ((lane>>4)<<4));
      #pragma unroll
      for (int dt = 0; dt < 4; ++dt){
        b16x8 vf = *(const b16x8*)((const char*)vsh + (dt*16 + (lane&15))*432 + pt*64 + ((lane>>4)<<4));
        o[dt] = __builtin_amdgcn_mfma_f32_16x16x32_bf16(pa, vf, o[dt], 0, 0, 0);
      }
    }
    #pragma unroll
    for (int e = 0; e < 4; ++e){
      float pe[4];
      #pragma unroll
      for (int j = 0; j < 4; ++j) pe[j] = __shfl(pt12[j], (lane & 48) + e, 64);
      #pragma unroll
      for (int dt = 0; dt < 4; ++dt){
        b16 vv = *((const b16*)((const char*)vsh + (dt*16 + (lane&15))*432 + (192+e)*2));
        float vvf = (float)vv;
        #pragma unroll
        for (int j = 0; j < 4; ++j) o[dt][j] += pe[j]*vvf;
      }
    }
    #pragma unroll
    for (int dt = 0; dt < 4; ++dt)
      #pragma unroll
      for (int j = 0; j < 4; ++j){
        int n = n0 + ((lane>>4)<<2) + j;
        if (n < 196){
          long idx = ((long)(b*196 + n))*768 + h*64 + dt*16 + (lane&15);
          Ob[idx] = (b16)(av*o[dt][j] + cv);
        }
      }
  }
}

// ---------------------------------------------------------------- launch
extern "C" void kernel_launch(void* const* d_in, const int* in_sizes, int n_in,
                              void* d_out, int out_size, void* d_ws, size_t ws_size,
                              hipStream_t stream){
  const float* x         = (const float*)d_in[0];
  const float* W_qv      = (const float*)d_in[1];
  const float* k_ext     = (const float*)d_in[2];
  const float* attn_bias = (const float*)d_in[3];
  const float* bn_gamma  = (const float*)d_in[4];
  const float* bn_beta   = (const float*)d_in[5];
  const float* W_proj    = (const float*)d_in[6];
  const float* b_proj    = (const float*)d_in[7];
  float* out = (float*)d_out;

  char* ws = (char*)d_ws;
  const long SZ = 19267584;              // 9,633,792 bf16
  b16*   q_buf   = (b16*)(ws);
  b16*   v_buf   = (b16*)(ws + SZ);
  b16*   O_buf   = (b16*)(ws + 2*SZ);    // doubles as x_bf16 before k_attn
  b16*   x_bf16  = (b16*)(ws + 2*SZ);
  b16*   W_qvT   = (b16*)(ws + 3*SZ);
  b16*   W_projT = (b16*)(ws + 3*SZ + 2359296);
  float* Kmat    = (float*)(ws + 3*SZ + 3538944);   // 4096 f32
  float* ksum    = Kmat + 4096;                     // 64 f32
  float* stats   = ksum + 64;                       // 48 f32
  float* coef    = stats + 48;                      // 48 f32
  float* Ggram   = coef + 48;                       // 12*4096 f32

  hipMemsetAsync(stats, 0, 48*sizeof(float), stream);
  hipMemsetAsync(Ggram, 0, 12*4096*sizeof(float), stream);

  dim3 tb(32, 8);
  k_transpose_cvt<<<dim3(1536/32, 768/32), tb, 0, stream>>>(W_qv,   W_qvT,   768, 1536);
  k_transpose_cvt<<<dim3(768/32,  768/32), tb, 0, stream>>>(W_proj, W_projT, 768, 768);
  k_cvt<<<4704, 256, 0, stream>>>(x, x_bf16);
  k_kprep<<<4, 256, 0, stream>>>(k_ext, Kmat, ksum);
  k_gemm<0><<<98*12, 256, 0, stream>>>(x_bf16, W_qvT, q_buf, v_buf, nullptr, nullptr, ksum, stats);
  k_gram<<<384, 256, 0, stream>>>(q_buf, Ggram);
  k_sfin<<<12, 256, 0, stream>>>(Ggram, Kmat, stats, bn_gamma, bn_beta, coef);
  k_attn<<<768, 256, 0, stream>>>(q_buf, v_buf, k_ext, attn_bias, coef, O_buf);
  k_gemm<1><<<98*6, 256, 0, stream>>>(O_buf, W_projT, nullptr, nullptr, out, b_proj, nullptr, nullptr);
}

// Round 5
// 189.164 us; speedup vs baseline: 1.4706x; 1.0558x over previous
//
#include <hip/hip_runtime.h>
#include <hip/hip_bf16.h>

typedef __bf16 b16;
typedef __bf16 b16x8 __attribute__((ext_vector_type(8)));
typedef float  f32x4 __attribute__((ext_vector_type(4)));

#define B_   64
#define N_   196
#define C_   768
#define H_   12
#define HD_  64
#define TOK  (B_*N_)      // 12544
#define SCALE 0.125f

// async global->LDS, 16B per lane, wave-uniform LDS base
__device__ __forceinline__ void gl_lds16(const void* g, void* l){
  __builtin_amdgcn_global_load_lds((const __attribute__((address_space(1))) void*)g,
                                   (__attribute__((address_space(3))) void*)l, 16, 0, 0);
}

// ---------------------------------------------------------------- transpose+cvt
__global__ __launch_bounds__(256) void k_transpose_cvt(const float* __restrict__ in,
                                                       b16* __restrict__ out, int R, int C){
  __shared__ b16 tile[32][33];
  int tx = threadIdx.x, ty = threadIdx.y;
  int bx = blockIdx.x, by = blockIdx.y;
  int c = bx*32 + tx;
  #pragma unroll
  for (int i = 0; i < 32; i += 8){
    int r = by*32 + ty + i;
    tile[ty+i][tx] = (b16)in[(long)r*C + c];
  }
  __syncthreads();
  int rr = by*32 + tx;
  #pragma unroll
  for (int i = 0; i < 32; i += 8){
    int cc = bx*32 + ty + i;
    out[(long)cc*R + rr] = tile[tx][ty+i];
  }
}

// ---------------------------------------------------------------- x f32 -> bf16
__global__ __launch_bounds__(256) void k_cvt(const float* __restrict__ in, b16* __restrict__ out){
  long i = ((long)blockIdx.x*256 + threadIdx.x)*8;
  const float4* s = (const float4*)(in + i);
  float4 f0 = s[0], f1 = s[1];
  b16x8 v; v[0]=(b16)f0.x; v[1]=(b16)f0.y; v[2]=(b16)f0.z; v[3]=(b16)f0.w;
           v[4]=(b16)f1.x; v[5]=(b16)f1.y; v[6]=(b16)f1.z; v[7]=(b16)f1.w;
  *(b16x8*)(out + i) = v;
}

// ---------------------------------------------------------------- K = k^T k, ksum (4 blocks)
__global__ __launch_bounds__(256) void k_kprep(const float* __restrict__ k_ext,
                                               float* __restrict__ Kmat, float* __restrict__ ksum){
  __shared__ float ks[N_][HD_];
  int tid = threadIdx.x, blk = blockIdx.x;       // blk 0..3
  for (int i = tid; i < N_*HD_; i += 256) ks[i/HD_][i%HD_] = k_ext[i];
  __syncthreads();
  int i = tid >> 2;
  int j0 = blk*16 + (tid & 3)*4;
  float a0=0.f, a1=0.f, a2=0.f, a3=0.f;
  for (int p = 0; p < N_; ++p){
    float ki = ks[p][i];
    float4 kv = *(const float4*)&ks[p][j0];
    a0 += ki*kv.x; a1 += ki*kv.y; a2 += ki*kv.z; a3 += ki*kv.w;
  }
  Kmat[i*64+j0+0]=a0; Kmat[i*64+j0+1]=a1; Kmat[i*64+j0+2]=a2; Kmat[i*64+j0+3]=a3;
  if (blk == 0 && tid < 64){
    float s = 0.f;
    for (int p = 0; p < N_; ++p) s += ks[p][tid];
    ksum[tid] = s;
  }
}

// ---------------------------------------------------------------- tiled bf16 MFMA GEMM
// counted-vmcnt schedule (T4): stage depth 2, never drain vmcnt to 0 mid-loop.
// Pre-swizzled source + swizzled read (verified conflict-free, round 4).
// MODE0: scatter q/v bf16 [b,h,n,d] + fused BN stats; MODE1: f32 out + bias
template<int MODE>
__global__ __launch_bounds__(256) void k_gemm(const b16* __restrict__ A,
                                              const b16* __restrict__ BT,
                                              b16* __restrict__ qout, b16* __restrict__ vout,
                                              float* __restrict__ fout, const float* __restrict__ bias,
                                              const float* __restrict__ ksum, float* __restrict__ stats){
  const int NT  = (MODE == 0) ? 12 : 6;
  const int NWG = 98*NT;
  // bijective XCD swizzle (m204)
  int orig = blockIdx.x;
  int q8 = NWG >> 3, r8 = NWG & 7;
  int xcd = orig & 7, loc = orig >> 3;
  int bid = (xcd < r8 ? xcd*(q8+1) : r8*(q8+1) + (xcd-r8)*q8) + loc;
  int rt = bid / NT, ct = bid % NT;
  int brow = rt*128, bcol = ct*128;

  __shared__ b16 sm[2][2][128*32];   // [buf][A/B], 32 KiB
  int tid = threadIdx.x, lane = tid & 63, w = tid >> 6;
  int wr = w >> 1, wc = w & 1;

  int rsub = w*16 + (lane>>2);
  int gsrc = (lane & 3) ^ ((lane >> 3) & 3);
  const b16* gA = A  + (long)(brow + rsub)*768 + gsrc*8;
  const b16* gB = BT + (long)(bcol + rsub)*768 + gsrc*8;
  b16* lA0 = &sm[0][0][w*16*32];
  b16* lB0 = &sm[0][1][w*16*32];
  b16* lA1 = &sm[1][0][w*16*32];
  b16* lB1 = &sm[1][1][w*16*32];

#define STAGE(la, lb, kt) do{ \
    gl_lds16(gA + (kt)*32,            (la));        \
    gl_lds16(gA + (kt)*32 + 64*768,   (la) + 64*32);\
    gl_lds16(gB + (kt)*32,            (lb));        \
    gl_lds16(gB + (kt)*32 + 64*768,   (lb) + 64*32);\
  } while(0)

#define COMPUTE(cur) do{ \
    const char* smA = (const char*)sm[cur][0]; \
    const char* smB = (const char*)sm[cur][1]; \
    b16x8 af[4], bf[4]; \
    _Pragma("unroll") \
    for (int m = 0; m < 4; ++m){ \
      int row = wr*64 + m*16 + (lane & 15); \
      af[m] = *(const b16x8*)(smA + row*64 + (((lane>>4) ^ ((row>>1)&3))<<4)); \
    } \
    _Pragma("unroll") \
    for (int n = 0; n < 4; ++n){ \
      int row = wc*64 + n*16 + (lane & 15); \
      bf[n] = *(const b16x8*)(smB + row*64 + (((lane>>4) ^ ((row>>1)&3))<<4)); \
    } \
    _Pragma("unroll") \
    for (int m = 0; m < 4; ++m) \
      _Pragma("unroll") \
      for (int n = 0; n < 4; ++n) \
        acc[m][n] = __builtin_amdgcn_mfma_f32_16x16x32_bf16(af[m], bf[n], acc[m][n], 0, 0, 0); \
  } while(0)

  f32x4 acc[4][4];
  #pragma unroll
  for (int m = 0; m < 4; ++m)
    #pragma unroll
    for (int n = 0; n < 4; ++n) acc[m][n] = (f32x4){0.f,0.f,0.f,0.f};

  // prologue: tiles 0 and 1 in flight
  STAGE(lA0, lB0, 0);
  STAGE(lA1, lB1, 1);

  #pragma unroll 1
  for (int kt = 0; kt < 23; ++kt){
    int cur = kt & 1;
    asm volatile("s_waitcnt vmcnt(4)" ::: "memory");   // tile kt landed; kt+1 still in flight
    __builtin_amdgcn_s_barrier();
    asm volatile("" ::: "memory");
    COMPUTE(cur);
    asm volatile("" ::: "memory");
    __builtin_amdgcn_s_barrier();                       // all waves done reading buf cur
    asm volatile("" ::: "memory");
    if (kt < 22){
      if (cur == 0) STAGE(lA0, lB0, kt+2);
      else          STAGE(lA1, lB1, kt+2);
    }
  }
  // peeled last iteration (kt = 23): drain
  asm volatile("s_waitcnt vmcnt(0)" ::: "memory");
  __builtin_amdgcn_s_barrier();
  asm volatile("" ::: "memory");
  COMPUTE(1);
#undef COMPUTE
#undef STAGE

  if constexpr (MODE == 0){
    #pragma unroll
    for (int m = 0; m < 4; ++m){
      #pragma unroll
      for (int n = 0; n < 4; ++n){
        int col = bcol + wc*64 + n*16 + (lane & 15);
        int two = (col >= 768) ? 1 : 0;
        int hc = col - two*768;
        int hh = hc >> 6, d = hc & 63;
        b16* dst = two ? vout : qout;
        #pragma unroll
        for (int j = 0; j < 4; ++j){
          int r2 = brow + wr*64 + m*16 + ((lane>>4)<<2) + j;
          int bq = r2 / 196;
          int nn = r2 - bq*196;
          dst[((bq*12 + hh)*196 + nn)*64 + d] = (b16)acc[m][n][j];
        }
      }
    }
    // fused BN stats: per wave all cols belong to ONE head
    {
      bool isV = (bcol >= 768);
      float a_acc = 0.f, b_acc = 0.f;
      #pragma unroll
      for (int n = 0; n < 4; ++n){
        int d = n*16 + (lane & 15);
        float s = 0.f, s2 = 0.f;
        #pragma unroll
        for (int m = 0; m < 4; ++m)
          #pragma unroll
          for (int j = 0; j < 4; ++j){
            float v = acc[m][n][j];
            s += v; s2 += v*v;
          }
        if (isV){ a_acc += s; b_acc += s2; }
        else      a_acc += s * ksum[d];
      }
      #pragma unroll
      for (int off = 1; off < 64; off <<= 1){
        a_acc += __shfl_xor(a_acc, off, 64);
        b_acc += __shfl_xor(b_acc, off, 64);
      }
      if (lane == 0){
        if (isV){
          int hv = 2*(ct - 6) + wc;
          atomicAdd(&stats[24 + hv], a_acc);
          atomicAdd(&stats[36 + hv], b_acc);
        } else {
          int hq = 2*ct + wc;
          atomicAdd(&stats[hq], a_acc);
        }
      }
    }
  } else {
    #pragma unroll
    for (int m = 0; m < 4; ++m){
      #pragma unroll
      for (int n = 0; n < 4; ++n){
        int col = bcol + wc*64 + n*16 + (lane & 15);
        float bv = bias[col];
        #pragma unroll
        for (int j = 0; j < 4; ++j){
          int r2 = brow + wr*64 + m*16 + ((lane>>4)<<2) + j;
          fout[(long)r2*768 + col] = acc[m][n][j] + bv;
        }
      }
    }
  }
}

// ---------------------------------------------------------------- per-head Gram G = sum_t q q^T (MFMA)
__global__ __launch_bounds__(256) void k_gram(const b16* __restrict__ qb, float* __restrict__ G){
  __shared__ b16 qT[64*232];          // [d][t] stride 232
  int tid = threadIdx.x, lane = tid & 63, w = tid >> 6;
  int h = blockIdx.x % 12, bg = blockIdx.x / 12;   // bg 0..31
  f32x4 acc[4];
  #pragma unroll
  for (int n = 0; n < 4; ++n) acc[n] = (f32x4){0.f,0.f,0.f,0.f};
  #pragma unroll 1
  for (int r = 0; r < 2; ++r){
    int b = bg*2 + r;
    const b16* src = qb + ((long)(b*12 + h))*196*64;
    int d = lane;
    for (int p0 = w*8; p0 < 224; p0 += 32){
      b16x8 w8;
      #pragma unroll
      for (int j = 0; j < 8; ++j){
        int p = p0 + j;
        w8[j] = (p < 196) ? src[p*64 + d] : (b16)0.f;
      }
      *(b16x8*)(qT + d*232 + p0) = w8;
    }
    __syncthreads();
    #pragma unroll
    for (int ks = 0; ks < 7; ++ks){
      int t0 = ks*32;
      b16x8 af = *(const b16x8*)(qT + (16*w + (lane&15))*232 + t0 + ((lane>>4)<<3));
      #pragma unroll
      for (int n = 0; n < 4; ++n){
        b16x8 bf = *(const b16x8*)(qT + (16*n + (lane&15))*232 + t0 + ((lane>>4)<<3));
        acc[n] = __builtin_amdgcn_mfma_f32_16x16x32_bf16(af, bf, acc[n], 0, 0, 0);
      }
    }
    __syncthreads();
  }
  float* Gh = G + h*4096;
  #pragma unroll
  for (int n = 0; n < 4; ++n)
    #pragma unroll
    for (int j = 0; j < 4; ++j){
      int i  = 16*w + ((lane>>4)<<2) + j;
      int jj = 16*n + (lane&15);
      atomicAdd(&Gh[i*64 + jj], acc[n][j]);
    }
}

// ---------------------------------------------------------------- S2 = <G,K>, finalize coefs
__global__ __launch_bounds__(256) void k_sfin(const float* __restrict__ G, const float* __restrict__ Kmat,
                                              const float* __restrict__ stats, const float* __restrict__ gamma,
                                              const float* __restrict__ beta, float* __restrict__ coef){
  int h = blockIdx.x, tid = threadIdx.x;
  const float* Gh = G + h*4096;
  float s = 0.f;
  #pragma unroll
  for (int k = 0; k < 16; ++k) s += Gh[tid + k*256]*Kmat[tid + k*256];
  #pragma unroll
  for (int off = 1; off < 64; off <<= 1) s += __shfl_xor(s, off, 64);
  __shared__ float red[4];
  if ((tid & 63) == 0) red[tid>>6] = s;
  __syncthreads();
  if (tid == 0){
    float S2 = red[0]+red[1]+red[2]+red[3];
    const float cntS = 2458624.f, cntV = 802816.f;
    float S1 = stats[h], VS = stats[24+h], VS2 = stats[36+h];
    float ms = S1/cntS;
    float vars = S2/cntS - ms*ms;
    float alpha = gamma[h]*SCALE*rsqrtf(vars + 1e-5f);
    float mv = VS/cntV;
    float varv = VS2/cntV - mv*mv;
    float a = gamma[h]*rsqrtf(varv + 1e-5f);
    coef[h*4+0] = alpha;
    coef[h*4+1] = a;
    coef[h*4+2] = beta[h] - a*mv;
  }
}

// ---------------------------------------------------------------- fused attention per (b,h)
__global__ __launch_bounds__(256, 2) void k_attn(const b16* __restrict__ qb, const b16* __restrict__ vb,
                                                 const float* __restrict__ k_ext,
                                                 const float* __restrict__ attn_bias,
                                                 const float* __restrict__ coef,
                                                 b16* __restrict__ Ob){
  __shared__ b16 ksh[196*64];
  __shared__ b16 vsh[64*216];
  __shared__ b16 psh[4][16*200];
  __shared__ float bsh[196];

  int tid = threadIdx.x, lane = tid & 63, wid = tid >> 6;
  int bh = blockIdx.x;
  int h = bh % 12, b = bh / 12;
  const b16* qt = qb + (long)bh*N_*64;
  const b16* vt = vb + (long)bh*N_*64;
  float alpha = coef[h*4+0], av = coef[h*4+1], cv = coef[h*4+2];

  for (int c = tid; c < 196*8; c += 256){
    int p = c >> 3, g = c & 7;
    const float4* src = (const float4*)(k_ext + p*64 + g*8);
    float4 f0 = src[0], f1 = src[1];
    b16x8 v; v[0]=(b16)f0.x; v[1]=(b16)f0.y; v[2]=(b16)f0.z; v[3]=(b16)f0.w;
             v[4]=(b16)f1.x; v[5]=(b16)f1.y; v[6]=(b16)f1.z; v[7]=(b16)f1.w;
    *(b16x8*)((char*)ksh + p*128 + ((g ^ (p&7))<<4)) = v;
  }
  for (int p = tid; p < 196; p += 256) bsh[p] = attn_bias[p]*SCALE;
  {
    int d = tid & 63;
    for (int p0 = (tid>>6)*8; p0 < 196; p0 += 32){
      b16x8 w;
      #pragma unroll
      for (int j = 0; j < 8; ++j){
        int p = p0 + j;
        w[j] = (p < 196) ? vt[p*64 + d] : (b16)0.f;
      }
      *(b16x8*)((char*)vsh + d*432 + p0*2) = w;
    }
  }
  __syncthreads();

  for (int rt = wid; rt < 13; rt += 4){
    int n0 = rt*16;
    int qrow = n0 + (lane & 15); if (qrow > 195) qrow = 195;
    b16x8 a0 = *(const b16x8*)((const char*)qt + qrow*128 +      ((lane>>4)<<4));
    b16x8 a1 = *(const b16x8*)((const char*)qt + qrow*128 + 64 + ((lane>>4)<<4));

    f32x4 sc[13];
    #pragma unroll
    for (int ct = 0; ct < 13; ++ct){
      int p = ct*16 + (lane & 15); int pc = p > 195 ? 195 : p;
      b16x8 b0 = *(const b16x8*)((const char*)ksh + pc*128 + ((( (lane>>4))   ^ (pc&7))<<4));
      b16x8 b1 = *(const b16x8*)((const char*)ksh + pc*128 + (((4+(lane>>4))  ^ (pc&7))<<4));
      f32x4 z = {0.f,0.f,0.f,0.f};
      z = __builtin_amdgcn_mfma_f32_16x16x32_bf16(a0, b0, z, 0, 0, 0);
      z = __builtin_amdgcn_mfma_f32_16x16x32_bf16(a1, b1, z, 0, 0, 0);
      sc[ct] = z;
    }
    int pcol = lane & 15;
    float mx[4] = {-1e30f,-1e30f,-1e30f,-1e30f};
    #pragma unroll
    for (int ct = 0; ct < 13; ++ct){
      int p = ct*16 + pcol;
      bool valid = (p < 196);
      float badd = valid ? bsh[p < 196 ? p : 0] : 0.f;
      #pragma unroll
      for (int j = 0; j < 4; ++j){
        float lv = valid ? (sc[ct][j]*alpha + badd) : -1e30f;
        sc[ct][j] = lv;
        mx[j] = fmaxf(mx[j], lv);
      }
    }
    #pragma unroll
    for (int off = 1; off < 16; off <<= 1)
      #pragma unroll
      for (int j = 0; j < 4; ++j) mx[j] = fmaxf(mx[j], __shfl_xor(mx[j], off, 64));
    float sm[4] = {0.f,0.f,0.f,0.f};
    #pragma unroll
    for (int ct = 0; ct < 13; ++ct)
      #pragma unroll
      for (int j = 0; j < 4; ++j){
        float e = __expf(sc[ct][j] - mx[j]);
        sc[ct][j] = e; sm[j] += e;
      }
    #pragma unroll
    for (int off = 1; off < 16; off <<= 1)
      #pragma unroll
      for (int j = 0; j < 4; ++j) sm[j] += __shfl_xor(sm[j], off, 64);
    float rs[4];
    #pragma unroll
    for (int j = 0; j < 4; ++j) rs[j] = 1.f/sm[j];

    b16* pw = psh[wid];
    #pragma unroll
    for (int ct = 0; ct < 12; ++ct){
      int p = ct*16 + pcol;
      #pragma unroll
      for (int j = 0; j < 4; ++j){
        int r = ((lane>>4)<<2) + j;
        pw[r*200 + p] = (b16)(sc[ct][j]*rs[j]);
      }
    }
    float pt12[4];
    #pragma unroll
    for (int j = 0; j < 4; ++j) pt12[j] = sc[12][j]*rs[j];

    __asm__ volatile("s_waitcnt lgkmcnt(0)" ::: "memory");
    __builtin_amdgcn_sched_barrier(0);

    f32x4 o[4];
    #pragma unroll
    for (int dt = 0; dt < 4; ++dt) o[dt] = (f32x4){0.f,0.f,0.f,0.f};
    #pragma unroll
    for (int pt = 0; pt < 6; ++pt){
      b16x8 pa = *(const b16x8*)((const char*)pw + (lane&15)*400 + pt*64 + ((lane>>4)<<4));
      #pragma unroll
      for (int dt = 0; dt < 4; ++dt){
        b16x8 vf = *(const b16x8*)((const char*)vsh + (dt*16 + (lane&15))*432 + pt*64 + ((lane>>4)<<4));
        o[dt] = __builtin_amdgcn_mfma_f32_16x16x32_bf16(pa, vf, o[dt], 0, 0, 0);
      }
    }
    #pragma unroll
    for (int e = 0; e < 4; ++e){
      float pe[4];
      #pragma unroll
      for (int j = 0; j < 4; ++j) pe[j] = __shfl(pt12[j], (lane & 48) + e, 64);
      #pragma unroll
      for (int dt = 0; dt < 4; ++dt){
        b16 vv = *((const b16*)((const char*)vsh + (dt*16 + (lane&15))*432 + (192+e)*2));
        float vvf = (float)vv;
        #pragma unroll
        for (int j = 0; j < 4; ++j) o[dt][j] += pe[j]*vvf;
      }
    }
    #pragma unroll
    for (int dt = 0; dt < 4; ++dt)
      #pragma unroll
      for (int j = 0; j < 4; ++j){
        int n = n0 + ((lane>>4)<<2) + j;
        if (n < 196){
          long idx = ((long)(b*196 + n))*768 + h*64 + dt*16 + (lane&15);
          Ob[idx] = (b16)(av*o[dt][j] + cv);
        }
      }
  }
}

// ---------------------------------------------------------------- launch
extern "C" void kernel_launch(void* const* d_in, const int* in_sizes, int n_in,
                              void* d_out, int out_size, void* d_ws, size_t ws_size,
                              hipStream_t stream){
  const float* x         = (const float*)d_in[0];
  const float* W_qv      = (const float*)d_in[1];
  const float* k_ext     = (const float*)d_in[2];
  const float* attn_bias = (const float*)d_in[3];
  const float* bn_gamma  = (const float*)d_in[4];
  const float* bn_beta   = (const float*)d_in[5];
  const float* W_proj    = (const float*)d_in[6];
  const float* b_proj    = (const float*)d_in[7];
  float* out = (float*)d_out;

  char* ws = (char*)d_ws;
  const long SZ = 19267584;              // 9,633,792 bf16
  b16*   q_buf   = (b16*)(ws);
  b16*   v_buf   = (b16*)(ws + SZ);
  b16*   O_buf   = (b16*)(ws + 2*SZ);    // doubles as x_bf16 before k_attn
  b16*   x_bf16  = (b16*)(ws + 2*SZ);
  b16*   W_qvT   = (b16*)(ws + 3*SZ);
  b16*   W_projT = (b16*)(ws + 3*SZ + 2359296);
  float* Kmat    = (float*)(ws + 3*SZ + 3538944);   // 4096 f32
  float* ksum    = Kmat + 4096;                     // 64 f32
  float* stats   = ksum + 64;                       // 48 f32
  float* coef    = stats + 48;                      // 48 f32
  float* Ggram   = coef + 48;                       // 12*4096 f32

  hipMemsetAsync(stats, 0, 48*sizeof(float), stream);
  hipMemsetAsync(Ggram, 0, 12*4096*sizeof(float), stream);

  dim3 tb(32, 8);
  k_transpose_cvt<<<dim3(1536/32, 768/32), tb, 0, stream>>>(W_qv,   W_qvT,   768, 1536);
  k_transpose_cvt<<<dim3(768/32,  768/32), tb, 0, stream>>>(W_proj, W_projT, 768, 768);
  k_cvt<<<4704, 256, 0, stream>>>(x, x_bf16);
  k_kprep<<<4, 256, 0, stream>>>(k_ext, Kmat, ksum);
  k_gemm<0><<<98*12, 256, 0, stream>>>(x_bf16, W_qvT, q_buf, v_buf, nullptr, nullptr, ksum, stats);
  k_gram<<<384, 256, 0, stream>>>(q_buf, Ggram);
  k_sfin<<<12, 256, 0, stream>>>(Ggram, Kmat, stats, bn_gamma, bn_beta, coef);
  k_attn<<<768, 256, 0, stream>>>(q_buf, v_buf, k_ext, attn_bias, coef, O_buf);
  k_gemm<1><<<98*6, 256, 0, stream>>>(O_buf, W_projT, nullptr, nullptr, out, b_proj, nullptr, nullptr);
}